// Round 14
// baseline (39510.352 us; speedup 1.0000x reference)
//
#include <hip/hip_runtime.h>
#include <math.h>

#define BB 64
#define TT 512
#define HH 512
#define KK 512
#define G3 1536
#define PEN 0.7f
#define NBLK 256
#define NTHR 1024
#define SLAB 32768               // 64*512 floats (one h slab)
#define WSTRIDE ((size_t)(G3 * KK))

// ---------------------------------------------------------------------------
// sc0 sc1 = bypass L1+L2 (MALL-coherent).
__device__ __forceinline__ float4 ld4b(const float* p) {
  float4 r; asm volatile("global_load_dwordx4 %0, %1, off sc0 sc1" : "=v"(r) : "v"(p)); return r;
}
__device__ __forceinline__ void ld1b(float* d, const float* p) {
  asm volatile("global_load_dword %0, %1, off sc0 sc1" : "=v"(*d) : "v"(p));
}
__device__ __forceinline__ void stwt1(float* p, float v) {
  asm volatile("global_store_dword %0, %1, off sc0 sc1" :: "v"(p), "v"(v) : "memory");
}
__device__ __forceinline__ void vwait0() {
  asm volatile("s_waitcnt vmcnt(0)" ::: "memory");
  __builtin_amdgcn_sched_barrier(0);
}
__device__ __forceinline__ unsigned umin2(unsigned a, unsigned b) { return a < b ? a : b; }
__device__ __forceinline__ void st_flag(unsigned* p, unsigned v) {
  __hip_atomic_store(p, v, __ATOMIC_RELAXED, __HIP_MEMORY_SCOPE_AGENT);
}
__device__ __forceinline__ void poll_all(const unsigned* flags, unsigned ep) {
  const unsigned* p = flags + (threadIdx.x & 63) * 4;
  for (;;) {
    uint4 v; asm volatile("global_load_dwordx4 %0, %1, off sc0 sc1" : "=v"(v) : "v"(p));
    asm volatile("s_waitcnt vmcnt(0)" ::: "memory");
    unsigned mn = umin2(umin2(v.x, v.y), umin2(v.z, v.w));
    if (__all((int)(mn >= ep))) break;
    __builtin_amdgcn_s_sleep(2);
  }
}
__device__ __forceinline__ void poll8(const unsigned* flag8, unsigned ep) {
  const unsigned* p = flag8 + (threadIdx.x & 7);
  for (;;) {
    unsigned v; asm volatile("global_load_dword %0, %1, off sc0 sc1" : "=v"(v) : "v"(p));
    asm volatile("s_waitcnt vmcnt(0)" ::: "memory");
    if (__all((int)(v >= ep))) break;
    __builtin_amdgcn_s_sleep(2);
  }
}
__device__ __forceinline__ void poll32(const unsigned* base, unsigned ep) {
  const unsigned* p = base + (threadIdx.x & 31);
  for (;;) {
    unsigned v; asm volatile("global_load_dword %0, %1, off sc0 sc1" : "=v"(v) : "v"(p));
    asm volatile("s_waitcnt vmcnt(0)" ::: "memory");
    if (__all((int)(v >= ep))) break;
    __builtin_amdgcn_s_sleep(2);
  }
}

// ---------------------------------------------------------------------------
// pre 1: xc[t][s] = sum_b x[b,t,:] . Wsel[s,512:] + B*bsel[s]
__global__ void k_pre_xc(const float* __restrict__ x, const float* __restrict__ Wsel,
                         const float* __restrict__ bsel, float* __restrict__ xc) {
  int t = blockIdx.x, tid = threadIdx.x;
  __shared__ float xs[512];
  __shared__ float a0[256], a1[256], a2[256];
  for (int i = tid; i < 512; i += 256) {
    float s = 0.f;
    const float* px = x + (size_t)t * KK + i;
    for (int b = 0; b < BB; ++b) s += px[(size_t)b * TT * KK];
    xs[i] = s;
  }
  __syncthreads();
  float c0 = 0.f, c1 = 0.f, c2 = 0.f;
  for (int i = tid; i < 512; i += 256) {
    float v = xs[i];
    c0 += v * Wsel[512 + i];
    c1 += v * Wsel[1024 + 512 + i];
    c2 += v * Wsel[2048 + 512 + i];
  }
  a0[tid] = c0; a1[tid] = c1; a2[tid] = c2;
  __syncthreads();
  for (int off = 128; off; off >>= 1) {
    if (tid < off) { a0[tid] += a0[tid + off]; a1[tid] += a1[tid + off]; a2[tid] += a2[tid + off]; }
    __syncthreads();
  }
  if (tid == 0) {
    xc[t * 4 + 0] = a0[0] + 64.f * bsel[0];
    xc[t * 4 + 1] = a1[0] + 64.f * bsel[1];
    xc[t * 4 + 2] = a2[0] + 64.f * bsel[2];
  }
}

// pre 2: wsum/bsum + zero sync words (plain stores; visible to next dispatch)
__global__ void k_pre_misc(const float* __restrict__ Wlw, const float* __restrict__ blw,
                           float* __restrict__ wsum, float* __restrict__ bsumb,
                           unsigned* __restrict__ flags, unsigned* __restrict__ flag8,
                           float* __restrict__ plog) {
  int tid = threadIdx.x;
  if (tid < 256) flags[tid] = 0u;
  if (tid < 8) flag8[tid] = 0u;
  if (tid < 24) plog[tid] = 0.f;
  for (int h = tid; h < 512; h += 256) {
    float s = 0.f;
    for (int g = 0; g < 512; ++g) s += Wlw[(size_t)g * 512 + h];
    wsum[h] = s;
  }
  __shared__ float red[256];
  float s = 0.f;
  for (int i = tid; i < 512; i += 256) s += blw[i];
  red[tid] = s;
  __syncthreads();
  for (int off = 128; off; off >>= 1) {
    if (tid < off) red[tid] += red[tid + off];
    __syncthreads();
  }
  if (tid == 0) *bsumb = red[0];
}

// ---------------------------------------------------------------------------
// One GRU layer, 2-D tiled: block = 16 j (jt) x 8 b (bt); 1024 threads.
// wave w = jl (uniform -> uniform weight row base); lane = ks*8 + bl.
// Stage: A/H tiles (8b x 512k, 16 KB each) -> LDS layout [c][ks][bl] so a
// wave's compute read (fixed c) is 64 consecutive float4s = 1 KB contiguous.
// AMODE: 1 = row-major cached (x), 0 = transposed slab bypass (h0).
// HMODE: 1 = row-major cached (out[t-1]), 0 = transposed slab bypass (h0).
template<int AMODE, int HMODE>
__device__ __forceinline__ void do_layer(
    int tid, int w, int ks, int bl, int jt, int bt, int lidx,
    const float* __restrict__ aSrc, size_t aStride,
    const float* __restrict__ hSrc, size_t hStride, int zh,
    const float* __restrict__ Wih, const float* __restrict__ Whh,
    const float* __restrict__ bih_l, const float* __restrict__ bhh_l,
    const float* __restrict__ wsum, const float* __restrict__ Wsel,
    float* __restrict__ houtT, float* __restrict__ outN, float* __restrict__ outN2,
    float* __restrict__ part,
    float4* As3, float4* Hs3, float* red) {
  // ---- stage (1 float4 per tile per thread) ----
  {
    int k4 = tid >> 3, b = tid & 7;
    int li = (k4 & 15) * 64 + (k4 >> 4) * 8 + b;
    float4 av, hv4;
    if (AMODE == 1) av = *(const float4*)(aSrc + (size_t)b * aStride + k4 * 4);
    else            av = ld4b(aSrc + k4 * 256 + (bt * 8 + b) * 4);
    if (zh)              hv4 = make_float4(0.f, 0.f, 0.f, 0.f);
    else if (HMODE == 1) hv4 = *(const float4*)(hSrc + (size_t)b * hStride + k4 * 4);
    else                 hv4 = ld4b(hSrc + k4 * 256 + (bt * 8 + b) * 4);
    vwait0();           // bypass-load results are not tracked by the compiler
    As3[li] = av;
    Hs3[li] = hv4;
  }
  __syncthreads();

  // ---- compute: 1 j x 8 b-lane x K-slice 64 per thread ----
  {
    int j = jt * 16 + w;
    const float* q0 = Wih + (size_t)j * KK + ks * 64;
    const float* q1 = q0 + (size_t)512 * KK;
    const float* q2 = q1 + (size_t)512 * KK;
    const float* q3 = Whh + (size_t)j * KK + ks * 64;
    const float* q4 = q3 + (size_t)512 * KK;
    const float* q5 = q4 + (size_t)512 * KK;
    const float4* Ab = As3 + ks * 8 + bl;
    const float4* Hb = Hs3 + ks * 8 + bl;
    float aI0 = 0.f, aI1 = 0.f, aI2 = 0.f, aH0 = 0.f, aH1 = 0.f, aH2 = 0.f;
#pragma unroll
    for (int c = 0; c < 16; ++c) {
      float4 a4 = Ab[c * 64];
      float4 h4 = Hb[c * 64];
      float4 u;
#define DOTW(acc, ptr, vv) u = *(const float4*)((ptr) + c * 4); \
      acc += vv.x * u.x + vv.y * u.y + vv.z * u.z + vv.w * u.w;
      DOTW(aI0, q0, a4) DOTW(aI1, q1, a4) DOTW(aI2, q2, a4)
      DOTW(aH0, q3, h4) DOTW(aH1, q4, h4) DOTW(aH2, q5, h4)
#undef DOTW
    }
    int rb = (ks * 128 + w * 8 + bl) * 6;
    red[rb + 0] = aI0; red[rb + 1] = aI1; red[rb + 2] = aI2;
    red[rb + 3] = aH0; red[rb + 4] = aH1; red[rb + 5] = aH2;
  }
  __syncthreads();

  // ---- epilogue: 128 threads = 16 jl x 8 b ----
  if (tid < 128) {
    int jl = tid >> 3, ble = tid & 7;
    int je = jt * 16 + jl;
    int bg = bt * 8 + ble;
    float sI0 = 0.f, sI1 = 0.f, sI2 = 0.f, sH0 = 0.f, sH1 = 0.f, sH2 = 0.f;
#pragma unroll
    for (int kss = 0; kss < 8; ++kss) {
      int o = (kss * 128 + jl * 8 + ble) * 6;
      sI0 += red[o]; sI1 += red[o + 1]; sI2 += red[o + 2];
      sH0 += red[o + 3]; sH1 += red[o + 4]; sH2 += red[o + 5];
    }
    float air = sI0 + bih_l[je],        ahr = sH0 + bhh_l[je];
    float aiz = sI1 + bih_l[je + 512],  ahz = sH1 + bhh_l[je + 512];
    float ain = sI2 + bih_l[je + 1024], ahn = sH2 + bhh_l[je + 1024];
    float rg = 1.f / (1.f + expf(-(air + ahr)));
    float zg = 1.f / (1.f + expf(-(aiz + ahz)));
    float ng = tanhf(ain + rg * ahn);
    int kp = je >> 2;
    float hpv = ((const float*)&Hs3[(kp & 15) * 64 + (kp >> 4) * 8 + ble])[je & 3];
    float hv = (1.f - zg) * ng + zg * hpv;
    if (houtT) stwt1(houtT + (je >> 2) * 256 + bg * 4 + (je & 3), hv);
    if (outN)  stwt1(outN + (size_t)bg * HH + je, hv);
    if (outN2) stwt1(outN2 + (size_t)bg * HH + je, hv);
    red[6144 + 0 * 128 + tid] = hv * wsum[je];
    red[6144 + 1 * 128 + tid] = hv * Wsel[je];
    red[6144 + 2 * 128 + tid] = hv * Wsel[1024 + je];
    red[6144 + 3 * 128 + tid] = hv * Wsel[2048 + je];
  }
  __syncthreads();
  if (tid < 8) {
#pragma unroll
    for (int g = 0; g < 4; ++g) {
      float s = 0.f;
#pragma unroll
      for (int jl = 0; jl < 16; ++jl) s += red[6144 + g * 128 + jl * 8 + tid];
      stwt1(part + ((size_t)(g * 128 + lidx * 64 + bt * 8 + tid)) * 32 + jt, s);
    }
    vwait0();
  }
}

// ---------------------------------------------------------------------------
__global__ __launch_bounds__(NTHR, 4) void k_persist(
    const float* __restrict__ x,
    const float* __restrict__ Wih_first, const float* __restrict__ Wih_rest,
    const float* __restrict__ Whh,
    const float* __restrict__ bih, const float* __restrict__ bhh,
    const float* __restrict__ Wsel,
    const float* __restrict__ wsum, const float* __restrict__ bsumb,
    const float* __restrict__ xc,
    float* __restrict__ h0T, float* __restrict__ part, float* __restrict__ plog,
    float* __restrict__ out,
    unsigned* __restrict__ flags, unsigned* __restrict__ flag8) {
  __shared__ float4 As3[1024];          // 16 KB
  __shared__ float4 Hs3[1024];          // 16 KB
  __shared__ float red[6144 + 512];     // 26.6 KB: wave partials + r2 / router / reducer scratch
  int tid = threadIdx.x, bid = blockIdx.x;
  int jt = bid & 31, bt = bid >> 5;     // 32 jt x 8 bt; same-jt blocks share an XCD
  int w = __builtin_amdgcn_readfirstlane(tid >> 6);  // = jl, wave-uniform
  int lane = tid & 63;
  int bl = lane & 7, ks = lane >> 3;
  float p0 = PEN, p1 = 1.f, p2 = 1.f;
  int cur = 0;

  if (tid == 0)
    (void)__hip_atomic_load(&flags[0], __ATOMIC_ACQUIRE, __HIP_MEMORY_SCOPE_AGENT);
  __syncthreads();
  float bs = *bsumb;

  for (int t = 0; t < TT; ++t) {
    const float* h0rd = h0T + (size_t)((t + 1) & 1) * SLAB;  // h0(t-1)
    float* h0wr = h0T + (size_t)(t & 1) * SLAB;

    if (t > 0) {
      // ---- router (verbatim round 13: plog 8x3 partials, replicated) ----
      if (tid < 64) poll8(flag8, (unsigned)t);
      __syncthreads();
      if (tid < 24) { float v; ld1b(&v, plog + tid); vwait0(); red[tid] = v; }
      __syncthreads();
      float l0 = xc[4 * t + 0], l1 = xc[4 * t + 1], l2 = xc[4 * t + 2];
#pragma unroll
      for (int r = 0; r < 8; ++r) {
        l0 += red[r * 3 + 0]; l1 += red[r * 3 + 1]; l2 += red[r * 3 + 2];
      }
      float m = fmaxf(l0, fmaxf(l1, l2));
      float e0 = expf(l0 - m), e1 = expf(l1 - m), e2 = expf(l2 - m);
      float Z = e0 + e1 + e2;
      float w0_ = e0 / Z * p0, w1_ = e1 / Z * p1, w2_ = e2 / Z * p2;
      cur = 0; float bb_ = w0_;
      if (w1_ > bb_) { bb_ = w1_; cur = 1; }
      if (w2_ > bb_) { bb_ = w2_; cur = 2; }
      p0 *= (cur == 0) ? PEN : 1.f;
      p1 *= (cur == 1) ? PEN : 1.f;
      p2 *= (cur == 2) ? PEN : 1.f;
      float mx = fmaxf(p0, fmaxf(p1, p2));
      p0 /= mx; p1 /= mx; p2 /= mx;
      __syncthreads();
    }

    // ---- layer 0: A = x (row-major cached), H = h0(t-1) (slab bypass) ----
    do_layer<1, 0>(tid, w, ks, bl, jt, bt, 0,
                   x + (size_t)(bt * 8) * TT * KK + (size_t)t * KK, (size_t)TT * KK,
                   h0rd, 0, (t == 0),
                   Wih_first + (size_t)cur * WSTRIDE,
                   Whh + (size_t)(cur * 2) * WSTRIDE,
                   bih + (size_t)(cur * 2) * G3, bhh + (size_t)(cur * 2) * G3,
                   wsum, Wsel, h0wr, nullptr, nullptr, part, As3, Hs3, red);
    __syncthreads();
    if (tid == 0) st_flag(&flags[bid], 2u * (unsigned)t + 1u);
    // bt-group barrier: layer 1 needs all 32 jt blocks' h0 columns of this bt
    if (tid < 64) poll32(flags + bt * 32, 2u * (unsigned)t + 1u);
    __syncthreads();

    // ---- layer 1: A = h0new (slab bypass), H = out[t-1] (row-major cached,
    //      write-once per launch -> L2-cacheable after entry acquire) ----
    float* o2 = (t == TT - 1) ? (out + (size_t)TT * SLAB) : nullptr;
    do_layer<0, 1>(tid, w, ks, bl, jt, bt, 1,
                   h0wr, 0,
                   out + (size_t)(t - 1) * SLAB + (size_t)(bt * 8) * KK, (size_t)KK, (t == 0),
                   Wih_rest + (size_t)cur * WSTRIDE,
                   Whh + (size_t)(cur * 2 + 1) * WSTRIDE,
                   bih + (size_t)(cur * 2 + 1) * G3, bhh + (size_t)(cur * 2 + 1) * G3,
                   wsum, Wsel, nullptr, out + (size_t)t * SLAB, o2, part, As3, Hs3, red);
    __syncthreads();
    if (tid == 0) st_flag(&flags[bid], 2u * (unsigned)t + 2u);

    // ---- 8 reducer blocks: part[4][128][32] -> 3-float logit partials ----
    if (bid < 8 && t + 1 < TT) {
      if (tid < 64) poll_all(flags, 2u * (unsigned)t + 2u);
      __syncthreads();
      if (tid < 64) {
        int g = tid >> 4, rl = tid & 15;
        int row = bid * 16 + rl;
        float a[32];
#pragma unroll
        for (int q = 0; q < 32; ++q)
          ld1b(&a[q], part + ((size_t)(g * 128 + row)) * 32 + q);
        vwait0();
        float s = 0.f;
#pragma unroll
        for (int q = 0; q < 32; ++q) s += a[q];
        red[g * 16 + rl] = s;
      }
      __syncthreads();
      if (tid == 0) {
        // red[0..15]=D rows, [16..31]=e0, [32..47]=e1, [48..63]=e2 (round-13 form)
#pragma unroll
        for (int s_ = 0; s_ < 3; ++s_) {
          float acc = 0.f;
#pragma unroll
          for (int i = 0; i < 16; ++i) acc += (red[i] + bs) * red[(s_ + 1) * 16 + i];
          stwt1(plog + bid * 3 + s_, acc);
        }
        vwait0();
        st_flag(&flag8[bid], (unsigned)t + 1u);
      }
      __syncthreads();
    }
  }
}

// ---------------------------------------------------------------------------
extern "C" void kernel_launch(void* const* d_in, const int* in_sizes, int n_in,
                              void* d_out, int out_size, void* d_ws, size_t ws_size,
                              hipStream_t stream) {
  const float* x         = (const float*)d_in[0];
  const float* Wih_first = (const float*)d_in[1];
  const float* Wih_rest  = (const float*)d_in[2];
  const float* Whh       = (const float*)d_in[3];
  const float* bih       = (const float*)d_in[4];
  const float* bhh       = (const float*)d_in[5];
  const float* Wlw       = (const float*)d_in[6];
  const float* blw       = (const float*)d_in[7];
  const float* Wsel      = (const float*)d_in[8];
  const float* bsel      = (const float*)d_in[9];
  float* out = (float*)d_out;
  float* ws  = (float*)d_ws;

  float* xc       = ws;                       // 2048
  float* wsum     = ws + 2048;                // 512
  float* bsumb    = ws + 2560;                // 4
  unsigned* flags = (unsigned*)(ws + 2592);   // 256 (16B aligned)
  unsigned* flag8 = (unsigned*)(ws + 2848);   // 8
  float* plog     = ws + 2880;                // 24 (pad region to 4096)
  float* part     = ws + 4096;                // 4*128*32 = 16384 -> 20480
  float* h0T      = ws + 20480;               // 2*SLAB

  k_pre_xc<<<dim3(TT), 256, 0, stream>>>(x, Wsel, bsel, xc);
  k_pre_misc<<<dim3(1), 256, 0, stream>>>(Wlw, blw, wsum, bsumb, flags, flag8, plog);
  k_persist<<<dim3(NBLK), NTHR, 0, stream>>>(
      x, Wih_first, Wih_rest, Whh, bih, bhh, Wsel, wsum, bsumb, xc,
      h0T, part, plog, out, flags, flag8);
}